// Round 1
// baseline (100.444 us; speedup 1.0000x reference)
//
#include <hip/hip_runtime.h>

#define NROWS 32768        // B*H*W = 8*64*64
#define NELEM 262144       // B*C*H*W
#define KCB   8192
#define CHUNK 1024
#define NCHUNK (KCB / CHUNK)

// Kernel 1: for each row n and codebook chunk, find best (max score) entry.
// score_k = z . e_k - 0.5*||e_k||^2   (argmax score == argmin distance)
__global__ __launch_bounds__(256, 4) void vq_scan(
    const float* __restrict__ z, const float* __restrict__ cb,
    float2* __restrict__ part)
{
    __shared__ float4 se[CHUNK][2];   // codebook entries (8 floats each)
    __shared__ float  sh[CHUNK];      // 0.5*||e||^2

    const int t  = threadIdx.x;
    const int k0 = blockIdx.y * CHUNK;

    // Cooperative load of this chunk into LDS (+ norm precompute).
    #pragma unroll
    for (int i = 0; i < CHUNK / 256; ++i) {
        int e = i * 256 + t;
        const float4* p = (const float4*)(cb + (size_t)(k0 + e) * 8);
        float4 a = p[0], b = p[1];
        se[e][0] = a; se[e][1] = b;
        sh[e] = 0.5f * (a.x*a.x + a.y*a.y + a.z*a.z + a.w*a.w
                      + b.x*b.x + b.y*b.y + b.z*b.z + b.w*b.w);
    }
    __syncthreads();

    const int n   = blockIdx.x * 256 + t;
    const int b   = n >> 12;          // H*W = 4096
    const int rem = n & 4095;
    const float* zp = z + (size_t)b * 32768 + rem;   // C*H*W = 32768
    const float z0 = zp[0],     z1 = zp[4096],  z2 = zp[8192],  z3 = zp[12288];
    const float z4 = zp[16384], z5 = zp[20480], z6 = zp[24576], z7 = zp[28672];

    float best = -3.0e38f;
    int   bidx = 0;
    #pragma unroll 4
    for (int k = 0; k < CHUNK; ++k) {
        float4 ea = se[k][0], eb = se[k][1];
        float acc = fmaf(z0, ea.x, -sh[k]);
        acc = fmaf(z1, ea.y, acc);
        acc = fmaf(z2, ea.z, acc);
        acc = fmaf(z3, ea.w, acc);
        acc = fmaf(z4, eb.x, acc);
        acc = fmaf(z5, eb.y, acc);
        acc = fmaf(z6, eb.z, acc);
        acc = fmaf(z7, eb.w, acc);
        if (acc > best) { best = acc; bidx = k0 + k; }   // strict > keeps first (argmin tie rule)
    }
    float2 r; r.x = best; r.y = __int_as_float(bidx);
    part[(size_t)blockIdx.y * NROWS + n] = r;
}

// Kernel 2: combine the NCHUNK partials, gather codebook[best], write z_q (NCHW)
// and accumulate loss = 1.25 * mean((z_q - z)^2).
__global__ __launch_bounds__(256) void vq_emit(
    const float* __restrict__ z, const float* __restrict__ cb,
    const float2* __restrict__ part, float* __restrict__ out)
{
    const int t = threadIdx.x;
    const int n = blockIdx.x * 256 + t;

    float best = -3.0e38f;
    int   bidx = 0;
    #pragma unroll
    for (int c = 0; c < NCHUNK; ++c) {
        float2 r = part[(size_t)c * NROWS + n];
        if (r.x > best) { best = r.x; bidx = __float_as_int(r.y); }
    }

    const float4* ep = (const float4*)(cb + (size_t)bidx * 8);
    float4 ea = ep[0], eb = ep[1];
    float e[8] = {ea.x, ea.y, ea.z, ea.w, eb.x, eb.y, eb.z, eb.w};

    const int b = n >> 12, rem = n & 4095;
    const size_t base = (size_t)b * 32768 + rem;

    float sq = 0.0f;
    #pragma unroll
    for (int c = 0; c < 8; ++c) {
        float zz = z[base + (size_t)c * 4096];
        out[base + (size_t)c * 4096] = e[c];      // coalesced across threads per c
        float d = e[c] - zz;
        sq = fmaf(d, d, sq);
    }

    // wave(64)-level reduction, one atomic per wave
    #pragma unroll
    for (int o = 32; o > 0; o >>= 1) sq += __shfl_down(sq, o);
    if ((t & 63) == 0)
        atomicAdd(out + NELEM, sq * (1.25f / (float)NELEM));
}

extern "C" void kernel_launch(void* const* d_in, const int* in_sizes, int n_in,
                              void* d_out, int out_size, void* d_ws, size_t ws_size,
                              hipStream_t stream)
{
    const float* z  = (const float*)d_in[0];   // [8, 8, 64, 64]
    const float* cb = (const float*)d_in[1];   // [8192, 8]
    float* out = (float*)d_out;                // 262144 z_q + 1 loss
    float2* part = (float2*)d_ws;              // [NCHUNK][NROWS] (score, idx)

    hipMemsetAsync(out + NELEM, 0, sizeof(float), stream);

    dim3 g1(NROWS / 256, NCHUNK);
    vq_scan<<<g1, 256, 0, stream>>>(z, cb, part);
    vq_emit<<<NROWS / 256, 256, 0, stream>>>(z, cb, part, out);
}

// Round 2
// 86.868 us; speedup vs baseline: 1.1563x; 1.1563x over previous
//
#include <hip/hip_runtime.h>

typedef __attribute__((ext_vector_type(8))) short short8;
typedef __attribute__((ext_vector_type(4))) float f32x4;

#define NROWS 32768        // B*H*W
#define NELEM 262144       // B*C*H*W
#define KCB   8192
#define ROWS_PB 64
#define CHUNK 512          // entries per staged chunk (per k-group)
#define NCHU  8            // chunks per k-group (4096/512)

// round-to-nearest-even fp32 -> bf16 (values are small & finite; no NaN path)
static __device__ __forceinline__ short to_bf16(float x) {
    unsigned u = __float_as_uint(x);
    unsigned r = (u + 0x7FFFu + ((u >> 16) & 1u)) >> 16;
    return (short)r;
}

// Pack codebook: cbb[k] = 16 bf16: [e0..e7, -0.5*||e||^2, 0...]
__global__ __launch_bounds__(256) void vq_prep(const float* __restrict__ cb,
                                               short8* __restrict__ cbb) {
    int k = blockIdx.x * 256 + threadIdx.x;
    const float4* p = (const float4*)(cb + (size_t)k * 8);
    float4 a = p[0], b = p[1];
    float h = -0.5f * (a.x*a.x + a.y*a.y + a.z*a.z + a.w*a.w
                     + b.x*b.x + b.y*b.y + b.z*b.z + b.w*b.w);
    short8 lo = { to_bf16(a.x), to_bf16(a.y), to_bf16(a.z), to_bf16(a.w),
                  to_bf16(b.x), to_bf16(b.y), to_bf16(b.z), to_bf16(b.w) };
    short8 hi = { to_bf16(h), 0, 0, 0, 0, 0, 0, 0 };
    cbb[2 * k]     = lo;
    cbb[2 * k + 1] = hi;
}

// Fused: MFMA distance scan + argmax + gather + z_q write + loss.
// 8 waves/block: wave w -> row-tile (w&3), k-half (w>>2). 64 rows/block.
__global__ __launch_bounds__(512, 4) void vq_main(
    const float* __restrict__ z, const float* __restrict__ cb,
    const short8* __restrict__ cbb, float* __restrict__ out)
{
    __shared__ short8 sbuf[2][2][CHUNK * 2];   // [kgrp][dbuf][entries*2 halves] = 64 KB
    __shared__ float  sbest[2][ROWS_PB];
    __shared__ int    sidxs[2][ROWS_PB];

    const int tid    = threadIdx.x;
    const int lane   = tid & 63;
    const int w      = tid >> 6;
    const int rowgrp = w & 3;
    const int kgrp   = w >> 2;
    const int col    = lane & 15;
    const int g      = lane >> 4;
    const int gt     = tid & 255;          // thread within k-group (4 waves)

    // ---- A fragment: 16 z-rows, k-slots 0..7 = channels, slot 8 = 1.0 ----
    const int row = blockIdx.x * ROWS_PB + rowgrp * 16 + col;
    const int bb = row >> 12, hw = row & 4095;
    const float* zp = z + (size_t)bb * 32768 + hw;
    short8 afrag = {0, 0, 0, 0, 0, 0, 0, 0};
    if (g == 0) {
        afrag[0] = to_bf16(zp[0]);     afrag[1] = to_bf16(zp[4096]);
        afrag[2] = to_bf16(zp[8192]);  afrag[3] = to_bf16(zp[12288]);
        afrag[4] = to_bf16(zp[16384]); afrag[5] = to_bf16(zp[20480]);
        afrag[6] = to_bf16(zp[24576]); afrag[7] = to_bf16(zp[28672]);
    } else if (g == 1) {
        afrag[0] = (short)0x3F80;      // bf16(1.0)
    }                                  // g>=2: zeros (k=16..31 dead)

    const int kg_base = kgrp * (KCB / 2);
    const float4* cbv = (const float4*)cbb;

    // ---- stage chunk 0 ----
    float4 r0, r1, r2, r3;
    {
        const float4* s = cbv + (size_t)kg_base * 2;
        r0 = s[gt]; r1 = s[gt + 256]; r2 = s[gt + 512]; r3 = s[gt + 768];
        float4* d = (float4*)&sbuf[kgrp][0][0];
        d[gt] = r0; d[gt + 256] = r1; d[gt + 512] = r2; d[gt + 768] = r3;
    }
    __syncthreads();

    float best0 = -3e38f, best1 = -3e38f, best2 = -3e38f, best3 = -3e38f;
    int   bi0 = 0, bi1 = 0, bi2 = 0, bi3 = 0;
    const f32x4 zacc = {0.f, 0.f, 0.f, 0.f};

    for (int c = 0; c < NCHU; ++c) {
        const int buf = c & 1;
        if (c + 1 < NCHU) {
            const float4* s = cbv + (size_t)(kg_base + (c + 1) * CHUNK) * 2;
            r0 = s[gt]; r1 = s[gt + 256]; r2 = s[gt + 512]; r3 = s[gt + 768];
        }
        const short8* bp = &sbuf[kgrp][buf][(col << 1) | (g & 1)];
        int cand = kg_base + c * CHUNK + col;
        #pragma unroll 8
        for (int t = 0; t < CHUNK / 16; ++t) {       // 32 tiles
            short8 bfrag = bp[t * 32];
            f32x4 acc = __builtin_amdgcn_mfma_f32_16x16x32_bf16(afrag, bfrag, zacc, 0, 0, 0);
            if (acc[0] > best0) { best0 = acc[0]; bi0 = cand; }
            if (acc[1] > best1) { best1 = acc[1]; bi1 = cand; }
            if (acc[2] > best2) { best2 = acc[2]; bi2 = cand; }
            if (acc[3] > best3) { best3 = acc[3]; bi3 = cand; }
            cand += 16;
        }
        if (c + 1 < NCHU) {
            __syncthreads();                          // all waves done reading buf^1
            float4* d = (float4*)&sbuf[kgrp][buf ^ 1][0];
            d[gt] = r0; d[gt + 256] = r1; d[gt + 512] = r2; d[gt + 768] = r3;
            __syncthreads();                          // buf^1 ready for chunk c+1
        }
    }

    // ---- cross-lane argmax within each 16-lane col group ----
    #pragma unroll
    for (int d = 1; d < 16; d <<= 1) {
        float ob; int oi;
        ob = __shfl_xor(best0, d); oi = __shfl_xor(bi0, d);
        if (ob > best0 || (ob == best0 && oi < bi0)) { best0 = ob; bi0 = oi; }
        ob = __shfl_xor(best1, d); oi = __shfl_xor(bi1, d);
        if (ob > best1 || (ob == best1 && oi < bi1)) { best1 = ob; bi1 = oi; }
        ob = __shfl_xor(best2, d); oi = __shfl_xor(bi2, d);
        if (ob > best2 || (ob == best2 && oi < bi2)) { best2 = ob; bi2 = oi; }
        ob = __shfl_xor(best3, d); oi = __shfl_xor(bi3, d);
        if (ob > best3 || (ob == best3 && oi < bi3)) { best3 = ob; bi3 = oi; }
    }
    if (col == 0) {
        int rl = rowgrp * 16 + g * 4;      // C/D row = (lane>>4)*4 + reg
        sbest[kgrp][rl + 0] = best0; sidxs[kgrp][rl + 0] = bi0;
        sbest[kgrp][rl + 1] = best1; sidxs[kgrp][rl + 1] = bi1;
        sbest[kgrp][rl + 2] = best2; sidxs[kgrp][rl + 2] = bi2;
        sbest[kgrp][rl + 3] = best3; sidxs[kgrp][rl + 3] = bi3;
    }
    __syncthreads();

    // ---- emit: 64 rows x 8 ch = 512 elems, one per thread ----
    const int ch  = tid >> 6;
    const int pos = tid & 63;
    float b0 = sbest[0][pos], b1 = sbest[1][pos];
    int k = (b1 > b0) ? sidxs[1][pos] : sidxs[0][pos];   // tie -> lower k-half
    const int n = blockIdx.x * ROWS_PB + pos;
    const size_t o = ((size_t)(n >> 12)) * 32768 + (size_t)ch * 4096 + (n & 4095);
    float ev = cb[(size_t)k * 8 + ch];
    float zz = z[o];
    out[o] = ev;
    float dd = ev - zz;
    float sq = dd * dd;
    #pragma unroll
    for (int off2 = 32; off2 > 0; off2 >>= 1) sq += __shfl_down(sq, off2);
    if (lane == 0) atomicAdd(out + NELEM, sq * (1.25f / (float)NELEM));
}

extern "C" void kernel_launch(void* const* d_in, const int* in_sizes, int n_in,
                              void* d_out, int out_size, void* d_ws, size_t ws_size,
                              hipStream_t stream)
{
    const float* z  = (const float*)d_in[0];   // [8, 8, 64, 64]
    const float* cb = (const float*)d_in[1];   // [8192, 8]
    float* out = (float*)d_out;                // 262144 z_q + 1 loss
    short8* cbb = (short8*)d_ws;               // packed bf16 codebook, 256 KB

    hipMemsetAsync(out + NELEM, 0, sizeof(float), stream);
    vq_prep<<<KCB / 256, 256, 0, stream>>>(cb, cbb);
    vq_main<<<NROWS / ROWS_PB, 512, 0, stream>>>(z, cb, cbb, out);
}

// Round 3
// 33.612 us; speedup vs baseline: 2.9883x; 2.5844x over previous
//
#include <hip/hip_runtime.h>

typedef __attribute__((ext_vector_type(8))) short short8;
typedef __attribute__((ext_vector_type(4))) float f32x4;

#define NROWS 32768        // B*H*W
#define NELEM 262144       // B*C*H*W
#define KCB   8192

// round-to-nearest-even fp32 -> bf16 (finite values only)
static __device__ __forceinline__ short to_bf16(float x) {
    unsigned u = __float_as_uint(x);
    unsigned r = (u + 0x7FFFu + ((u >> 16) & 1u)) >> 16;
    return (short)r;
}

// Prep: pack codebook entries as 16 bf16 [e0..e7, -0.5*||e||^2, 0...] and
// z rows as 8 bf16; zero the loss slot. Grid covers KCB + NROWS threads.
__global__ __launch_bounds__(256) void vq_prep(
    const float* __restrict__ z, const float* __restrict__ cb,
    short8* __restrict__ cbb, short8* __restrict__ pka, float* __restrict__ out)
{
    int gid = blockIdx.x * 256 + threadIdx.x;
    if (gid == 0) out[NELEM] = 0.0f;
    if (gid < KCB) {
        const float4* p = (const float4*)(cb + (size_t)gid * 8);
        float4 a = p[0], b = p[1];
        float h = -0.5f * (a.x*a.x + a.y*a.y + a.z*a.z + a.w*a.w
                         + b.x*b.x + b.y*b.y + b.z*b.z + b.w*b.w);
        short8 lo = { to_bf16(a.x), to_bf16(a.y), to_bf16(a.z), to_bf16(a.w),
                      to_bf16(b.x), to_bf16(b.y), to_bf16(b.z), to_bf16(b.w) };
        short8 hi = { to_bf16(h), 0, 0, 0, 0, 0, 0, 0 };
        cbb[2 * gid]     = lo;
        cbb[2 * gid + 1] = hi;
    } else {
        int n = gid - KCB;                       // 0..NROWS-1
        int bb = n >> 12, hw = n & 4095;
        const float* zp = z + (size_t)bb * 32768 + hw;
        short8 v = { to_bf16(zp[0]),     to_bf16(zp[4096]),
                     to_bf16(zp[8192]),  to_bf16(zp[12288]),
                     to_bf16(zp[16384]), to_bf16(zp[20480]),
                     to_bf16(zp[24576]), to_bf16(zp[28672]) };
        pka[n] = v;
    }
}

// Main: 8 waves/block, 64 rows/block. Wave w scans private k-range
// [w*1024, w*1024+1024) with B-frags loaded straight global->VGPR (no LDS,
// no barriers in the scan). 4 A-frags (64 rows) amortize each B load over
// 4 MFMAs. Argmax via packed (score | inverted-index) + v_max_f32.
__global__ __launch_bounds__(512, 4) void vq_main(
    const float* __restrict__ z, const float* __restrict__ cb,
    const short8* __restrict__ cbb, const short8* __restrict__ pka,
    float* __restrict__ out)
{
    __shared__ float sbest[8][64];
    __shared__ float lsum[8];

    const int tid  = threadIdx.x;
    const int lane = tid & 63;
    const int w    = tid >> 6;        // k-wave 0..7
    const int col  = lane & 15;
    const int g    = lane >> 4;

    const int row0 = blockIdx.x * 64;

    // ---- A fragments: 4 row-tiles of 16; k-slots 0..7 = channels, 8 = 1.0 ----
    short8 af[4];
    #pragma unroll
    for (int f = 0; f < 4; ++f) {
        short8 v = {0, 0, 0, 0, 0, 0, 0, 0};
        if (g == 0)      v = pka[row0 + f * 16 + col];
        else if (g == 1) v[0] = (short)0x3F80;   // bf16(1.0) pairs with -0.5||e||^2
        af[f] = v;
    }

    const int kbase = w * 1024;
    const char* bp = (const char*)cbb + (size_t)(kbase + col) * 32
                                      + (size_t)(g & 1) * 16;

    float best[4][4];
    #pragma unroll
    for (int f = 0; f < 4; ++f)
        #pragma unroll
        for (int r = 0; r < 4; ++r)
            best[f][r] = __uint_as_float(0xFF800000u);   // -inf

    const unsigned inv0 = (unsigned)(8191 - (kbase + col));
    const f32x4 zacc = {0.f, 0.f, 0.f, 0.f};

    #pragma unroll 4
    for (int t = 0; t < 64; ++t) {               // 16 entries per tile
        short8 bf = *(const short8*)(bp + (size_t)t * 512);
        unsigned iv = inv0 - (unsigned)(t * 16); // inverted index, 13 bits
        #pragma unroll
        for (int f = 0; f < 4; ++f) {
            f32x4 acc = __builtin_amdgcn_mfma_f32_16x16x32_bf16(af[f], bf, zacc, 0, 0, 0);
            #pragma unroll
            for (int r = 0; r < 4; ++r) {
                // pack: truncated score | inverted idx -> argmax == 1 v_and_or + 1 v_max
                float p = __uint_as_float((__float_as_uint(acc[r]) & 0xFFFFE000u) | iv);
                best[f][r] = fmaxf(best[f][r], p);
            }
        }
    }

    // ---- cross-lane max within each 16-lane col group ----
    #pragma unroll
    for (int d = 1; d < 16; d <<= 1)
        #pragma unroll
        for (int f = 0; f < 4; ++f)
            #pragma unroll
            for (int r = 0; r < 4; ++r)
                best[f][r] = fmaxf(best[f][r], __shfl_xor(best[f][r], d));

    if (col == 0) {
        #pragma unroll
        for (int f = 0; f < 4; ++f)
            #pragma unroll
            for (int r = 0; r < 4; ++r)
                sbest[w][f * 16 + g * 4 + r] = best[f][r];   // row = g*4+r of tile f
    }
    __syncthreads();

    // ---- emit: 64 rows x 8 ch, one elem/thread ----
    const int pos = tid & 63;
    const int ch  = tid >> 6;
    float m = sbest[0][pos];
    #pragma unroll
    for (int kw = 1; kw < 8; ++kw) m = fmaxf(m, sbest[kw][pos]);
    const int k = 8191 - (int)(__float_as_uint(m) & 8191u);

    const int n = row0 + pos;
    const size_t o = ((size_t)(n >> 12)) * 32768 + (size_t)ch * 4096 + (size_t)(n & 4095);
    float ev = cb[(size_t)k * 8 + ch];
    float zz = z[o];
    out[o] = ev;
    float dd = ev - zz;
    float sq = dd * dd;
    #pragma unroll
    for (int off = 32; off > 0; off >>= 1) sq += __shfl_down(sq, off);
    if (lane == 0) lsum[w] = sq;
    __syncthreads();
    if (tid == 0) {
        float s = lsum[0] + lsum[1] + lsum[2] + lsum[3]
                + lsum[4] + lsum[5] + lsum[6] + lsum[7];
        atomicAdd(out + NELEM, s * (1.25f / (float)NELEM));
    }
}

extern "C" void kernel_launch(void* const* d_in, const int* in_sizes, int n_in,
                              void* d_out, int out_size, void* d_ws, size_t ws_size,
                              hipStream_t stream)
{
    const float* z  = (const float*)d_in[0];   // [8, 8, 64, 64] fp32
    const float* cb = (const float*)d_in[1];   // [8192, 8] fp32
    float* out = (float*)d_out;                // 262144 z_q + 1 loss
    short8* cbb = (short8*)d_ws;                       // 256 KB packed codebook
    short8* pka = (short8*)((char*)d_ws + 256 * 1024); // 512 KB packed z rows

    vq_prep<<<(KCB + NROWS) / 256, 256, 0, stream>>>(z, cb, cbb, pka, out);
    vq_main<<<NROWS / 64, 512, 0, stream>>>(z, cb, cbb, pka, out);
}